// Round 2
// baseline (1083.177 us; speedup 1.0000x reference)
//
#include <hip/hip_runtime.h>

#define SS 4096
#define NROWS 16384   // B*S

typedef __bf16 bf16;
typedef __attribute__((ext_vector_type(8))) __bf16 bf16x8;
typedef __attribute__((ext_vector_type(4))) float f32x4;

__device__ __forceinline__ float b2f(bf16 v) { return (float)v; }
__device__ __forceinline__ bf16  f2b(float f) { return (bf16)f; }

// ---------------------------------------------------------------- prep
// pos -> d_out[:,:3]; feat -> bf16 packed; sq[row] = sum(feat^2)
__global__ __launch_bounds__(256) void prep_kernel(
    const float* __restrict__ x, float* __restrict__ pos,
    bf16* __restrict__ featb, float* __restrict__ sq)
{
    int row = blockIdx.x, t = threadIdx.x;
    const float* xr = x + (size_t)row * 259;
    float v = xr[3 + t];
    featb[(size_t)row * 256 + t] = f2b(v);
    if (t < 3) pos[row * 3 + t] = xr[t];
    float s = v * v;
#pragma unroll
    for (int o = 32; o >= 1; o >>= 1) s += __shfl_xor(s, o);
    __shared__ float wsum[4];
    if ((t & 63) == 0) wsum[t >> 6] = s;
    __syncthreads();
    if (t == 0) sq[row] = wsum[0] + wsum[1] + wsum[2] + wsum[3];
}

// ---------------------------------------------------------------- weight prep (all tiny)
// C = A @ B, 256x256 fp32 row-major
__global__ void mm256_kernel(const float* __restrict__ A, const float* __restrict__ B,
                             float* __restrict__ C)
{
    int i = blockIdx.x, j = threadIdx.x;
    float acc = 0.f;
#pragma unroll 4
    for (int d = 0; d < 256; d++) acc += A[i * 256 + d] * B[d * 256 + j];
    C[i * 256 + j] = acc;
}

// outT[n][k] = sum_d fc1w[k][d] * M[d][n]  (BT layout of fc1w @ M, bf16)
__global__ void fuse_bT_kernel(const float* __restrict__ fc1w, const float* __restrict__ M,
                               bf16* __restrict__ outT)
{
    int n = blockIdx.x, k = threadIdx.x;
    float acc = 0.f;
#pragma unroll 4
    for (int d = 0; d < 256; d++) acc += fc1w[k * 256 + d] * M[d * 256 + n];
    outT[n * 256 + k] = f2b(acc);
}

// dst[n][k] = src[k][n]  (256x256, fp32 -> bf16)
__global__ void transpose_kernel(const float* __restrict__ src, bf16* __restrict__ dst)
{
    int n = blockIdx.x, k = threadIdx.x;
    dst[n * 256 + k] = f2b(src[k * 256 + n]);
}

// folded biases: qb[n] = fc1_b @ M1q + g1_b ; kb[n] = fc1_b @ M1k ; vb[n] = fc1_b @ wv
__global__ void biasfold_kernel(const float* __restrict__ fc1b, const float* __restrict__ M1q,
                                const float* __restrict__ M1k, const float* __restrict__ wvw,
                                const float* __restrict__ g1b, float* __restrict__ qb,
                                float* __restrict__ kb, float* __restrict__ vb)
{
    int n = threadIdx.x;
    float aq = 0.f, ak = 0.f, av = 0.f;
#pragma unroll 4
    for (int d = 0; d < 256; d++) {
        float f = fc1b[d];
        aq += f * M1q[d * 256 + n];
        ak += f * M1k[d * 256 + n];
        av += f * wvw[d * 256 + n];
    }
    qb[n] = aq + g1b[n];
    kb[n] = ak;
    vb[n] = av;
}

// ---------------------------------------------------------------- generic GEMM
// C[M x 256] = A[M x 256] @ B (given as BT[n][k]) ; K = 256.
// mode 0: bf16 out + bias.  mode 2: f32 out = acc + bias + x[r*259+3+c]
__global__ __launch_bounds__(256, 3) void gemm_kernel(
    const bf16* __restrict__ A, const bf16* __restrict__ BT,
    const float* __restrict__ bias, bf16* __restrict__ Ob,
    float* __restrict__ Of, const float* __restrict__ resid, int mode)
{
    int t = threadIdx.x, lane = t & 63, w = t >> 6, quad = lane >> 4, l15 = lane & 15;
    int row0 = blockIdx.y * 128 + (w >> 1) * 64;
    int col0 = blockIdx.x * 128 + (w & 1) * 64;
    f32x4 acc[4][4];
#pragma unroll
    for (int i = 0; i < 4; i++)
#pragma unroll
        for (int j = 0; j < 4; j++) acc[i][j] = (f32x4){0.f, 0.f, 0.f, 0.f};
    const bf16* Ap = A + (size_t)(row0 + l15) * 256 + quad * 8;
    const bf16* Bp = BT + (size_t)(col0 + l15) * 256 + quad * 8;
#pragma unroll
    for (int k = 0; k < 8; k++) {
        bf16x8 af[4], bfr[4];
#pragma unroll
        for (int mt = 0; mt < 4; mt++) af[mt] = *(const bf16x8*)(Ap + mt * 16 * 256 + k * 32);
#pragma unroll
        for (int nt = 0; nt < 4; nt++) bfr[nt] = *(const bf16x8*)(Bp + nt * 16 * 256 + k * 32);
#pragma unroll
        for (int mt = 0; mt < 4; mt++)
#pragma unroll
            for (int nt = 0; nt < 4; nt++)
                acc[mt][nt] = __builtin_amdgcn_mfma_f32_16x16x32_bf16(af[mt], bfr[nt], acc[mt][nt], 0, 0, 0);
    }
#pragma unroll
    for (int mt = 0; mt < 4; mt++)
#pragma unroll
        for (int nt = 0; nt < 4; nt++) {
            int rb = row0 + mt * 16 + quad * 4;
            int c = col0 + nt * 16 + l15;
            float bv = bias ? bias[c] : 0.0f;
#pragma unroll
            for (int reg = 0; reg < 4; reg++) {
                int r = rb + reg;
                float v = acc[mt][nt][reg] + bv;
                if (mode == 0) Ob[(size_t)r * 256 + c] = f2b(v);
                else Of[(size_t)r * 256 + c] = v + resid[(size_t)r * 259 + 3 + c];
            }
        }
}

// ---------------------------------------------------------------- fused gram + top-16 KNN
// Block: 64 query rows of one batch. Stream 256-col tiles: MFMA dots -> LDS
// (col-major, pad 68 -> conflict-free), then 4 threads/row streaming top-16.
// Selection key: sq[m] - 2*dot  (sq[n] shift doesn't change the argsort).
__global__ __launch_bounds__(256, 2) void knn_kernel(
    const bf16* __restrict__ featb, const float* __restrict__ sq, int* __restrict__ idxout)
{
    __shared__ float lds[256 * 68];   // 69632 B; reused for the final merge
    int t = threadIdx.x, lane = t & 63, w = t >> 6, quad = lane >> 4, l15 = lane & 15;
    int b = blockIdx.y;
    int row0 = blockIdx.x * 64;
    const bf16* F = featb + (size_t)b * SS * 256;
    const float* sqb = sq + b * SS;

    float tv[16]; int ti[16];
#pragma unroll
    for (int i = 0; i < 16; i++) { tv[i] = 3.0e38f; ti[i] = 0; }
    int selr = t >> 2, selq = t & 3;

    const bf16* Ap = F + (size_t)(row0 + l15) * 256 + quad * 8;

    for (int tile = 0; tile < 16; tile++) {
        int c0 = tile * 256;
        f32x4 acc[4][4];
#pragma unroll
        for (int i = 0; i < 4; i++)
#pragma unroll
            for (int j = 0; j < 4; j++) acc[i][j] = (f32x4){0.f, 0.f, 0.f, 0.f};
        const bf16* Bp = F + (size_t)(c0 + w * 64 + l15) * 256 + quad * 8;
#pragma unroll
        for (int k = 0; k < 8; k++) {
            bf16x8 af[4], bfr[4];
#pragma unroll
            for (int mt = 0; mt < 4; mt++) af[mt] = *(const bf16x8*)(Ap + mt * 16 * 256 + k * 32);
#pragma unroll
            for (int nt = 0; nt < 4; nt++) bfr[nt] = *(const bf16x8*)(Bp + nt * 16 * 256 + k * 32);
#pragma unroll
            for (int mt = 0; mt < 4; mt++)
#pragma unroll
                for (int nt = 0; nt < 4; nt++)
                    acc[mt][nt] = __builtin_amdgcn_mfma_f32_16x16x32_bf16(af[mt], bfr[nt], acc[mt][nt], 0, 0, 0);
        }
        __syncthreads();   // previous tile's selection reads are done
#pragma unroll
        for (int nt = 0; nt < 4; nt++) {
            int colL = w * 64 + nt * 16 + l15;
            float sqc = sqb[c0 + colL];
#pragma unroll
            for (int mt = 0; mt < 4; mt++) {
                f32x4 dv;
#pragma unroll
                for (int reg = 0; reg < 4; reg++) dv[reg] = fmaf(-2.0f, acc[mt][nt][reg], sqc);
                *(f32x4*)&lds[colL * 68 + mt * 16 + quad * 4] = dv;
            }
        }
        __syncthreads();
        // streaming selection: thread (selr, selq) scans cols selq+4j in increasing order
#pragma unroll 4
        for (int j = 0; j < 64; j++) {
            int cL = selq + 4 * j;
            float v = lds[cL * 68 + selr];
            if (v < tv[15]) {
                tv[15] = v; ti[15] = c0 + cL;
#pragma unroll
                for (int i2 = 14; i2 >= 0; i2--) {
                    if (tv[i2 + 1] < tv[i2]) {
                        float a_ = tv[i2]; tv[i2] = tv[i2 + 1]; tv[i2 + 1] = a_;
                        int b_ = ti[i2]; ti[i2] = ti[i2 + 1]; ti[i2 + 1] = b_;
                    }
                }
            }
        }
    }
    __syncthreads();
    // 4-way merge per row (lex (val, idx) keeps reference's stable-argsort order)
    float* lv = lds;
    int* li = (int*)(lds + 4096);
    int slot = selr * 4 + selq;
#pragma unroll
    for (int i = 0; i < 16; i++) { lv[slot * 16 + i] = tv[i]; li[slot * 16 + i] = ti[i]; }
    __syncthreads();
    if (t < 64) {
        int pq[4] = {0, 0, 0, 0};
        size_t obase = ((size_t)b * SS + row0 + t) * 16;
        for (int s = 0; s < 16; s++) {
            float bv = 3.3e38f; int bi = 0x7fffffff; int bq = 0;
#pragma unroll
            for (int q2 = 0; q2 < 4; q2++) {
                if (pq[q2] < 16) {
                    int o = (t * 4 + q2) * 16 + pq[q2];
                    float v = lv[o]; int ii = li[o];
                    if (v < bv || (v == bv && ii < bi)) { bv = v; bi = ii; bq = q2; }
                }
            }
            idxout[obase + s] = bi;
#pragma unroll
            for (int q2 = 0; q2 < 4; q2++) pq[q2] += (bq == q2) ? 1 : 0;
        }
    }
}

// ---------------------------------------------------------------- fused edge MLP
// per (b,n): E1 = relu(qb[n] - kg1[idx]); E2 = E1 @ g2 + b2; softmax over K;
// res[n] = sum_k attn * vf[idx]
__global__ __launch_bounds__(256, 2) void edge_kernel(
    const bf16* __restrict__ qb, const bf16* __restrict__ kg1, const bf16* __restrict__ vf,
    const bf16* __restrict__ g2T, const float* __restrict__ g2b,
    const int* __restrict__ idx, bf16* __restrict__ res)
{
    __shared__ __align__(16) bf16 e1[8 * 16 * 264];
    __shared__ int nbrs[8][16];
    int t = threadIdx.x, lane = t & 63, w = t >> 6, quad = lane >> 4, l15 = lane & 15;
    int G0 = blockIdx.x * 8;
    int bb = G0 & ~(SS - 1);
    if (t < 128) {
        int g = t >> 4, r = t & 15;
        nbrs[g][r] = bb + idx[(size_t)(G0 + g) * 16 + r];
    }
    bf16x8 bg[4][8];
#pragma unroll
    for (int nt = 0; nt < 4; nt++)
#pragma unroll
        for (int k = 0; k < 8; k++)
            bg[nt][k] = *(const bf16x8*)(g2T + (size_t)(w * 64 + nt * 16 + l15) * 256 + k * 32 + quad * 8);
    __syncthreads();
#pragma unroll 4
    for (int i = 0; i < 16; i++) {
        int f = i * 256 + t;
        int c8 = f & 31, r = (f >> 5) & 15, g = f >> 9;
        int nbr = nbrs[g][r];
        bf16x8 qv = *(const bf16x8*)(qb + (size_t)(G0 + g) * 256 + c8 * 8);
        bf16x8 kv = *(const bf16x8*)(kg1 + (size_t)nbr * 256 + c8 * 8);
        bf16x8 e;
#pragma unroll
        for (int j = 0; j < 8; j++) {
            float d = b2f(qv[j]) - b2f(kv[j]);
            e[j] = f2b(fmaxf(d, 0.0f));
        }
        *(bf16x8*)(&e1[(g * 16 + r) * 264 + c8 * 8]) = e;
    }
    __syncthreads();
#pragma unroll 1
    for (int g = 0; g < 8; g++) {
        f32x4 acc[4];
#pragma unroll
        for (int nt = 0; nt < 4; nt++) acc[nt] = (f32x4){0.f, 0.f, 0.f, 0.f};
#pragma unroll
        for (int k = 0; k < 8; k++) {
            bf16x8 a = *(const bf16x8*)(&e1[(g * 16 + l15) * 264 + k * 32 + quad * 8]);
#pragma unroll
            for (int nt = 0; nt < 4; nt++)
                acc[nt] = __builtin_amdgcn_mfma_f32_16x16x32_bf16(a, bg[nt][k], acc[nt], 0, 0, 0);
        }
        int grow = G0 + g;
#pragma unroll
        for (int nt = 0; nt < 4; nt++) {
            int col = w * 64 + nt * 16 + l15;
            float b2v = g2b[col];
            float lg[4], p[4];
#pragma unroll
            for (int reg = 0; reg < 4; reg++) lg[reg] = (acc[nt][reg] + b2v) * 0.0625f;
            float mx = fmaxf(fmaxf(lg[0], lg[1]), fmaxf(lg[2], lg[3]));
            mx = fmaxf(mx, __shfl_xor(mx, 16));
            mx = fmaxf(mx, __shfl_xor(mx, 32));
            float ps = 0.f;
#pragma unroll
            for (int reg = 0; reg < 4; reg++) { p[reg] = __expf(lg[reg] - mx); ps += p[reg]; }
            ps += __shfl_xor(ps, 16);
            ps += __shfl_xor(ps, 32);
            float inv = __builtin_amdgcn_rcpf(ps);
            float rs = 0.f;
#pragma unroll
            for (int reg = 0; reg < 4; reg++) {
                int nbr = nbrs[g][quad * 4 + reg];
                rs += p[reg] * b2f(vf[(size_t)nbr * 256 + col]);
            }
            rs *= inv;
            rs += __shfl_xor(rs, 16);
            rs += __shfl_xor(rs, 32);
            if (quad == 0) res[(size_t)grow * 256 + col] = f2b(rs);
        }
    }
}

// ---------------------------------------------------------------- launcher
extern "C" void kernel_launch(void* const* d_in, const int* in_sizes, int n_in,
                              void* d_out, int out_size, void* d_ws, size_t ws_size,
                              hipStream_t stream)
{
    (void)in_sizes; (void)n_in; (void)out_size; (void)ws_size;
    const float* x    = (const float*)d_in[0];
    const float* fc1w = (const float*)d_in[1];
    const float* fc1b = (const float*)d_in[2];
    const float* fc2w = (const float*)d_in[3];
    const float* fc2b = (const float*)d_in[4];
    const float* wqw  = (const float*)d_in[5];
    const float* wkw  = (const float*)d_in[6];
    const float* wvw  = (const float*)d_in[7];
    const float* g1w  = (const float*)d_in[8];
    const float* g1b  = (const float*)d_in[9];
    const float* g2w  = (const float*)d_in[10];
    const float* g2b  = (const float*)d_in[11];

    float* pos_out = (float*)d_out;
    float* out     = (float*)d_out + (size_t)NROWS * 3;

    char* ws = (char*)d_ws;
    size_t off = 0;
    auto alloc = [&](size_t bytes) { void* p = ws + off; off += (bytes + 255) & ~(size_t)255; return p; };
    bf16* featb = (bf16*)alloc((size_t)NROWS * 256 * 2);
    bf16* qbuf  = (bf16*)alloc((size_t)NROWS * 256 * 2);
    bf16* kg    = (bf16*)alloc((size_t)NROWS * 256 * 2);
    bf16* vf    = (bf16*)alloc((size_t)NROWS * 256 * 2);
    bf16* res   = (bf16*)alloc((size_t)NROWS * 256 * 2);
    float* sq   = (float*)alloc((size_t)NROWS * 4);
    int* idx    = (int*)alloc((size_t)NROWS * 16 * 4);
    float* M1q  = (float*)alloc(65536 * 4);
    float* M1k  = (float*)alloc(65536 * 4);
    bf16* WqT   = (bf16*)alloc(65536 * 2);
    bf16* WkT   = (bf16*)alloc(65536 * 2);
    bf16* WvT   = (bf16*)alloc(65536 * 2);
    bf16* fc2T  = (bf16*)alloc(65536 * 2);
    bf16* g2T   = (bf16*)alloc(65536 * 2);
    float* qbias = (float*)alloc(256 * 4);
    float* kbias = (float*)alloc(256 * 4);
    float* vbias = (float*)alloc(256 * 4);
    // total ~44 MB

    prep_kernel<<<NROWS, 256, 0, stream>>>(x, pos_out, featb, sq);

    // fused weights: Wq = fc1 @ wq @ g1 ; Wk = fc1 @ wk @ g1 ; Wv = fc1 @ wv
    mm256_kernel<<<256, 256, 0, stream>>>(wqw, g1w, M1q);
    mm256_kernel<<<256, 256, 0, stream>>>(wkw, g1w, M1k);
    fuse_bT_kernel<<<256, 256, 0, stream>>>(fc1w, M1q, WqT);
    fuse_bT_kernel<<<256, 256, 0, stream>>>(fc1w, M1k, WkT);
    fuse_bT_kernel<<<256, 256, 0, stream>>>(fc1w, wvw, WvT);
    biasfold_kernel<<<1, 256, 0, stream>>>(fc1b, M1q, M1k, wvw, g1b, qbias, kbias, vbias);
    transpose_kernel<<<256, 256, 0, stream>>>(fc2w, fc2T);
    transpose_kernel<<<256, 256, 0, stream>>>(g2w, g2T);

    dim3 gg(2, NROWS / 128);
    gemm_kernel<<<gg, 256, 0, stream>>>(featb, WqT, qbias, qbuf, nullptr, nullptr, 0);
    gemm_kernel<<<gg, 256, 0, stream>>>(featb, WkT, kbias, kg, nullptr, nullptr, 0);
    gemm_kernel<<<gg, 256, 0, stream>>>(featb, WvT, vbias, vf, nullptr, nullptr, 0);

    knn_kernel<<<dim3(SS / 64, 4), 256, 0, stream>>>(featb, sq, idx);

    edge_kernel<<<NROWS / 8, 256, 0, stream>>>(qbuf, kg, vf, g2T, g2b, idx, res);

    gemm_kernel<<<gg, 256, 0, stream>>>(res, fc2T, fc2b, nullptr, out, x, 2);
}

// Round 3
// 793.133 us; speedup vs baseline: 1.3657x; 1.3657x over previous
//
#include <hip/hip_runtime.h>

#define SS 4096
#define NROWS 16384   // B*S

typedef __bf16 bf16;
typedef __attribute__((ext_vector_type(8))) __bf16 bf16x8;
typedef __attribute__((ext_vector_type(4))) float f32x4;

__device__ __forceinline__ float b2f(bf16 v) { return (float)v; }
__device__ __forceinline__ bf16  f2b(float f) { return (bf16)f; }

// ---------------------------------------------------------------- prep
__global__ __launch_bounds__(256) void prep_kernel(
    const float* __restrict__ x, float* __restrict__ pos,
    bf16* __restrict__ featb, float* __restrict__ sq)
{
    int row = blockIdx.x, t = threadIdx.x;
    const float* xr = x + (size_t)row * 259;
    float v = xr[3 + t];
    featb[(size_t)row * 256 + t] = f2b(v);
    if (t < 3) pos[row * 3 + t] = xr[t];
    float s = v * v;
#pragma unroll
    for (int o = 32; o >= 1; o >>= 1) s += __shfl_xor(s, o);
    __shared__ float wsum[4];
    if ((t & 63) == 0) wsum[t >> 6] = s;
    __syncthreads();
    if (t == 0) sq[row] = wsum[0] + wsum[1] + wsum[2] + wsum[3];
}

// ---------------------------------------------------------------- weight prep (all tiny)
__global__ void mm256_kernel(const float* __restrict__ A, const float* __restrict__ B,
                             float* __restrict__ C)
{
    int i = blockIdx.x, j = threadIdx.x;
    float acc = 0.f;
#pragma unroll 4
    for (int d = 0; d < 256; d++) acc += A[i * 256 + d] * B[d * 256 + j];
    C[i * 256 + j] = acc;
}

__global__ void fuse_bT_kernel(const float* __restrict__ fc1w, const float* __restrict__ M,
                               bf16* __restrict__ outT)
{
    int n = blockIdx.x, k = threadIdx.x;
    float acc = 0.f;
#pragma unroll 4
    for (int d = 0; d < 256; d++) acc += fc1w[k * 256 + d] * M[d * 256 + n];
    outT[n * 256 + k] = f2b(acc);
}

__global__ void transpose_kernel(const float* __restrict__ src, bf16* __restrict__ dst)
{
    int n = blockIdx.x, k = threadIdx.x;
    dst[n * 256 + k] = f2b(src[k * 256 + n]);
}

__global__ void biasfold_kernel(const float* __restrict__ fc1b, const float* __restrict__ M1q,
                                const float* __restrict__ M1k, const float* __restrict__ wvw,
                                const float* __restrict__ g1b, float* __restrict__ qb,
                                float* __restrict__ kb, float* __restrict__ vb)
{
    int n = threadIdx.x;
    float aq = 0.f, ak = 0.f, av = 0.f;
#pragma unroll 4
    for (int d = 0; d < 256; d++) {
        float f = fc1b[d];
        aq += f * M1q[d * 256 + n];
        ak += f * M1k[d * 256 + n];
        av += f * wvw[d * 256 + n];
    }
    qb[n] = aq + g1b[n];
    kb[n] = ak;
    vb[n] = av;
}

// ---------------------------------------------------------------- generic GEMM
__global__ __launch_bounds__(256, 3) void gemm_kernel(
    const bf16* __restrict__ A, const bf16* __restrict__ BT,
    const float* __restrict__ bias, bf16* __restrict__ Ob,
    float* __restrict__ Of, const float* __restrict__ resid, int mode)
{
    int t = threadIdx.x, lane = t & 63, w = t >> 6, quad = lane >> 4, l15 = lane & 15;
    int row0 = blockIdx.y * 128 + (w >> 1) * 64;
    int col0 = blockIdx.x * 128 + (w & 1) * 64;
    f32x4 acc[4][4];
#pragma unroll
    for (int i = 0; i < 4; i++)
#pragma unroll
        for (int j = 0; j < 4; j++) acc[i][j] = (f32x4){0.f, 0.f, 0.f, 0.f};
    const bf16* Ap = A + (size_t)(row0 + l15) * 256 + quad * 8;
    const bf16* Bp = BT + (size_t)(col0 + l15) * 256 + quad * 8;
#pragma unroll
    for (int k = 0; k < 8; k++) {
        bf16x8 af[4], bfr[4];
#pragma unroll
        for (int mt = 0; mt < 4; mt++) af[mt] = *(const bf16x8*)(Ap + mt * 16 * 256 + k * 32);
#pragma unroll
        for (int nt = 0; nt < 4; nt++) bfr[nt] = *(const bf16x8*)(Bp + nt * 16 * 256 + k * 32);
#pragma unroll
        for (int mt = 0; mt < 4; mt++)
#pragma unroll
            for (int nt = 0; nt < 4; nt++)
                acc[mt][nt] = __builtin_amdgcn_mfma_f32_16x16x32_bf16(af[mt], bfr[nt], acc[mt][nt], 0, 0, 0);
    }
#pragma unroll
    for (int mt = 0; mt < 4; mt++)
#pragma unroll
        for (int nt = 0; nt < 4; nt++) {
            int rb = row0 + mt * 16 + quad * 4;
            int c = col0 + nt * 16 + l15;
            float bv = bias ? bias[c] : 0.0f;
#pragma unroll
            for (int reg = 0; reg < 4; reg++) {
                int r = rb + reg;
                float v = acc[mt][nt][reg] + bv;
                if (mode == 0) Ob[(size_t)r * 256 + c] = f2b(v);
                else Of[(size_t)r * 256 + c] = v + resid[(size_t)r * 259 + 3 + c];
            }
        }
}

// ---------------------------------------------------------------- fused gram + top-16 KNN
// Block: 64 query rows. Per 256-col tile: MFMA dots -> LDS row-major (stride 258,
// 2-way bank aliasing = free). Selection: wave-cooperative — each wave owns 16 rows;
// per row a sorted top-16 list lives across lanes 0..15 (sortable-u32 keys).
// Per 64-candidate chunk: ballot-filter vs current 16th (T); only qualifying
// candidates (~105 per row total) run the shuffle-shift insert.
// Key: sq[m] - 2*dot (the sq[n] shift doesn't change the per-row order);
// neighbor-set order is irrelevant downstream (softmax+sum over K are symmetric).
__global__ __launch_bounds__(256) void knn_kernel(
    const bf16* __restrict__ featb, const float* __restrict__ sq, int* __restrict__ idxout)
{
    __shared__ float lds[64 * 258];   // 66048 B
    int t = threadIdx.x, lane = t & 63, w = t >> 6, quad = lane >> 4, l15 = lane & 15;
    int b = blockIdx.y;
    int row0 = blockIdx.x * 64;
    const bf16* F = featb + (size_t)b * SS * 256;
    const float* sqb = sq + b * SS;

    unsigned int Lv[16]; int Li[16];
#pragma unroll
    for (int i = 0; i < 16; i++) { Lv[i] = 0xFFFFFFFFu; Li[i] = 0; }

    const bf16* Ap = F + (size_t)(row0 + l15) * 256 + quad * 8;

    for (int tile = 0; tile < 16; tile++) {
        int c0 = tile * 256;
        f32x4 acc[4][4];
#pragma unroll
        for (int i = 0; i < 4; i++)
#pragma unroll
            for (int j = 0; j < 4; j++) acc[i][j] = (f32x4){0.f, 0.f, 0.f, 0.f};
        const bf16* Bp = F + (size_t)(c0 + w * 64 + l15) * 256 + quad * 8;
#pragma unroll
        for (int k = 0; k < 8; k++) {
            bf16x8 af[4], bfr[4];
#pragma unroll
            for (int mt = 0; mt < 4; mt++) af[mt] = *(const bf16x8*)(Ap + mt * 16 * 256 + k * 32);
#pragma unroll
            for (int nt = 0; nt < 4; nt++) bfr[nt] = *(const bf16x8*)(Bp + nt * 16 * 256 + k * 32);
#pragma unroll
            for (int mt = 0; mt < 4; mt++)
#pragma unroll
                for (int nt = 0; nt < 4; nt++)
                    acc[mt][nt] = __builtin_amdgcn_mfma_f32_16x16x32_bf16(af[mt], bfr[nt], acc[mt][nt], 0, 0, 0);
        }
        __syncthreads();   // previous tile's selection reads are done
#pragma unroll
        for (int nt = 0; nt < 4; nt++) {
            int colL = w * 64 + nt * 16 + l15;
            float sqc = sqb[c0 + colL];
#pragma unroll
            for (int mt = 0; mt < 4; mt++) {
#pragma unroll
                for (int reg = 0; reg < 4; reg++) {
                    int rowL = mt * 16 + quad * 4 + reg;
                    lds[rowL * 258 + colL] = fmaf(-2.0f, acc[mt][nt][reg], sqc);
                }
            }
        }
        __syncthreads();
        // wave-cooperative selection: wave w owns LDS rows w*16 .. w*16+15
#pragma unroll 1
        for (int r = 0; r < 16; r++) {
            unsigned int Lv_r = Lv[r]; int Li_r = Li[r];
            unsigned int T = __shfl(Lv_r, 15);
#pragma unroll
            for (int c = 0; c < 4; c++) {
                float d = lds[(w * 16 + r) * 258 + c * 64 + lane];
                unsigned int bits = __float_as_uint(d);
                unsigned int key = bits ^ ((unsigned int)(((int)bits) >> 31) | 0x80000000u);
                unsigned long long mask = __ballot(key < T);
                int cbase = c0 + c * 64;
                while (mask) {
                    int l = __ffsll((unsigned long long)mask) - 1;
                    mask &= mask - 1;
                    unsigned int cv = __shfl(key, l);
                    if (cv < T) {
                        int ci = cbase + l;
                        bool qual = (lane < 16) && (cv < Lv_r);
                        unsigned long long m2 = __ballot(qual);
                        int pos = __ffsll((unsigned long long)m2) - 1;
                        unsigned int sv = __shfl_up(Lv_r, 1);
                        int si = __shfl_up(Li_r, 1);
                        Lv_r = (lane == pos) ? cv : ((lane > pos) ? sv : Lv_r);
                        Li_r = (lane == pos) ? ci : ((lane > pos) ? si : Li_r);
                        T = __shfl(Lv_r, 15);
                    }
                }
            }
            Lv[r] = Lv_r; Li[r] = Li_r;
        }
    }
    // write out: lanes 0..15 hold the 16 nearest (ascending) for each row
#pragma unroll 1
    for (int r = 0; r < 16; r++) {
        if (lane < 16)
            idxout[((size_t)b * SS + row0 + w * 16 + r) * 16 + lane] = Li[r];
    }
}

// ---------------------------------------------------------------- fused edge MLP
__global__ __launch_bounds__(256, 2) void edge_kernel(
    const bf16* __restrict__ qb, const bf16* __restrict__ kg1, const bf16* __restrict__ vf,
    const bf16* __restrict__ g2T, const float* __restrict__ g2b,
    const int* __restrict__ idx, bf16* __restrict__ res)
{
    __shared__ __align__(16) bf16 e1[8 * 16 * 264];
    __shared__ int nbrs[8][16];
    int t = threadIdx.x, lane = t & 63, w = t >> 6, quad = lane >> 4, l15 = lane & 15;
    int G0 = blockIdx.x * 8;
    int bb = G0 & ~(SS - 1);
    if (t < 128) {
        int g = t >> 4, r = t & 15;
        nbrs[g][r] = bb + idx[(size_t)(G0 + g) * 16 + r];
    }
    bf16x8 bg[4][8];
#pragma unroll
    for (int nt = 0; nt < 4; nt++)
#pragma unroll
        for (int k = 0; k < 8; k++)
            bg[nt][k] = *(const bf16x8*)(g2T + (size_t)(w * 64 + nt * 16 + l15) * 256 + k * 32 + quad * 8);
    __syncthreads();
#pragma unroll 4
    for (int i = 0; i < 16; i++) {
        int f = i * 256 + t;
        int c8 = f & 31, r = (f >> 5) & 15, g = f >> 9;
        int nbr = nbrs[g][r];
        bf16x8 qv = *(const bf16x8*)(qb + (size_t)(G0 + g) * 256 + c8 * 8);
        bf16x8 kv = *(const bf16x8*)(kg1 + (size_t)nbr * 256 + c8 * 8);
        bf16x8 e;
#pragma unroll
        for (int j = 0; j < 8; j++) {
            float d = b2f(qv[j]) - b2f(kv[j]);
            e[j] = f2b(fmaxf(d, 0.0f));
        }
        *(bf16x8*)(&e1[(g * 16 + r) * 264 + c8 * 8]) = e;
    }
    __syncthreads();
#pragma unroll 1
    for (int g = 0; g < 8; g++) {
        f32x4 acc[4];
#pragma unroll
        for (int nt = 0; nt < 4; nt++) acc[nt] = (f32x4){0.f, 0.f, 0.f, 0.f};
#pragma unroll
        for (int k = 0; k < 8; k++) {
            bf16x8 a = *(const bf16x8*)(&e1[(g * 16 + l15) * 264 + k * 32 + quad * 8]);
#pragma unroll
            for (int nt = 0; nt < 4; nt++)
                acc[nt] = __builtin_amdgcn_mfma_f32_16x16x32_bf16(a, bg[nt][k], acc[nt], 0, 0, 0);
        }
        int grow = G0 + g;
#pragma unroll
        for (int nt = 0; nt < 4; nt++) {
            int col = w * 64 + nt * 16 + l15;
            float b2v = g2b[col];
            float lg[4], p[4];
#pragma unroll
            for (int reg = 0; reg < 4; reg++) lg[reg] = (acc[nt][reg] + b2v) * 0.0625f;
            float mx = fmaxf(fmaxf(lg[0], lg[1]), fmaxf(lg[2], lg[3]));
            mx = fmaxf(mx, __shfl_xor(mx, 16));
            mx = fmaxf(mx, __shfl_xor(mx, 32));
            float ps = 0.f;
#pragma unroll
            for (int reg = 0; reg < 4; reg++) { p[reg] = __expf(lg[reg] - mx); ps += p[reg]; }
            ps += __shfl_xor(ps, 16);
            ps += __shfl_xor(ps, 32);
            float inv = __builtin_amdgcn_rcpf(ps);
            float rs = 0.f;
#pragma unroll
            for (int reg = 0; reg < 4; reg++) {
                int nbr = nbrs[g][quad * 4 + reg];
                rs += p[reg] * b2f(vf[(size_t)nbr * 256 + col]);
            }
            rs *= inv;
            rs += __shfl_xor(rs, 16);
            rs += __shfl_xor(rs, 32);
            if (quad == 0) res[(size_t)grow * 256 + col] = f2b(rs);
        }
    }
}

// ---------------------------------------------------------------- launcher
extern "C" void kernel_launch(void* const* d_in, const int* in_sizes, int n_in,
                              void* d_out, int out_size, void* d_ws, size_t ws_size,
                              hipStream_t stream)
{
    (void)in_sizes; (void)n_in; (void)out_size; (void)ws_size;
    const float* x    = (const float*)d_in[0];
    const float* fc1w = (const float*)d_in[1];
    const float* fc1b = (const float*)d_in[2];
    const float* fc2w = (const float*)d_in[3];
    const float* fc2b = (const float*)d_in[4];
    const float* wqw  = (const float*)d_in[5];
    const float* wkw  = (const float*)d_in[6];
    const float* wvw  = (const float*)d_in[7];
    const float* g1w  = (const float*)d_in[8];
    const float* g1b  = (const float*)d_in[9];
    const float* g2w  = (const float*)d_in[10];
    const float* g2b  = (const float*)d_in[11];

    float* pos_out = (float*)d_out;
    float* out     = (float*)d_out + (size_t)NROWS * 3;

    char* ws = (char*)d_ws;
    size_t off = 0;
    auto alloc = [&](size_t bytes) { void* p = ws + off; off += (bytes + 255) & ~(size_t)255; return p; };
    bf16* featb = (bf16*)alloc((size_t)NROWS * 256 * 2);
    bf16* qbuf  = (bf16*)alloc((size_t)NROWS * 256 * 2);
    bf16* kg    = (bf16*)alloc((size_t)NROWS * 256 * 2);
    bf16* vf    = (bf16*)alloc((size_t)NROWS * 256 * 2);
    bf16* res   = (bf16*)alloc((size_t)NROWS * 256 * 2);
    float* sq   = (float*)alloc((size_t)NROWS * 4);
    int* idx    = (int*)alloc((size_t)NROWS * 16 * 4);
    float* M1q  = (float*)alloc(65536 * 4);
    float* M1k  = (float*)alloc(65536 * 4);
    bf16* WqT   = (bf16*)alloc(65536 * 2);
    bf16* WkT   = (bf16*)alloc(65536 * 2);
    bf16* WvT   = (bf16*)alloc(65536 * 2);
    bf16* fc2T  = (bf16*)alloc(65536 * 2);
    bf16* g2T   = (bf16*)alloc(65536 * 2);
    float* qbias = (float*)alloc(256 * 4);
    float* kbias = (float*)alloc(256 * 4);
    float* vbias = (float*)alloc(256 * 4);

    prep_kernel<<<NROWS, 256, 0, stream>>>(x, pos_out, featb, sq);

    mm256_kernel<<<256, 256, 0, stream>>>(wqw, g1w, M1q);
    mm256_kernel<<<256, 256, 0, stream>>>(wkw, g1w, M1k);
    fuse_bT_kernel<<<256, 256, 0, stream>>>(fc1w, M1q, WqT);
    fuse_bT_kernel<<<256, 256, 0, stream>>>(fc1w, M1k, WkT);
    fuse_bT_kernel<<<256, 256, 0, stream>>>(fc1w, wvw, WvT);
    biasfold_kernel<<<1, 256, 0, stream>>>(fc1b, M1q, M1k, wvw, g1b, qbias, kbias, vbias);
    transpose_kernel<<<256, 256, 0, stream>>>(fc2w, fc2T);
    transpose_kernel<<<256, 256, 0, stream>>>(g2w, g2T);

    dim3 gg(2, NROWS / 128);
    gemm_kernel<<<gg, 256, 0, stream>>>(featb, WqT, qbias, qbuf, nullptr, nullptr, 0);
    gemm_kernel<<<gg, 256, 0, stream>>>(featb, WkT, kbias, kg, nullptr, nullptr, 0);
    gemm_kernel<<<gg, 256, 0, stream>>>(featb, WvT, vbias, vf, nullptr, nullptr, 0);

    knn_kernel<<<dim3(SS / 64, 4), 256, 0, stream>>>(featb, sq, idx);

    edge_kernel<<<NROWS / 8, 256, 0, stream>>>(qbuf, kg, vf, g2T, g2b, idx, res);

    gemm_kernel<<<gg, 256, 0, stream>>>(res, fc2T, fc2b, nullptr, out, x, 2);
}

// Round 4
// 610.756 us; speedup vs baseline: 1.7735x; 1.2986x over previous
//
#include <hip/hip_runtime.h>

#define SS 4096
#define NROWS 16384   // B*S

typedef __bf16 bf16;
typedef __attribute__((ext_vector_type(8))) __bf16 bf16x8;
typedef __attribute__((ext_vector_type(4))) float f32x4;

__device__ __forceinline__ float b2f(bf16 v) { return (float)v; }
__device__ __forceinline__ bf16  f2b(float f) { return (bf16)f; }

// ---------------------------------------------------------------- prep
__global__ __launch_bounds__(256) void prep_kernel(
    const float* __restrict__ x, float* __restrict__ pos,
    bf16* __restrict__ featb, float* __restrict__ sq)
{
    int row = blockIdx.x, t = threadIdx.x;
    const float* xr = x + (size_t)row * 259;
    float v = xr[3 + t];
    featb[(size_t)row * 256 + t] = f2b(v);
    if (t < 3) pos[row * 3 + t] = xr[t];
    float s = v * v;
#pragma unroll
    for (int o = 32; o >= 1; o >>= 1) s += __shfl_xor(s, o);
    __shared__ float wsum[4];
    if ((t & 63) == 0) wsum[t >> 6] = s;
    __syncthreads();
    if (t == 0) sq[row] = wsum[0] + wsum[1] + wsum[2] + wsum[3];
}

// ---------------------------------------------------------------- weight prep (all tiny)
__global__ void mm256_kernel(const float* __restrict__ A, const float* __restrict__ B,
                             float* __restrict__ C)
{
    int i = blockIdx.x, j = threadIdx.x;
    float acc = 0.f;
#pragma unroll 4
    for (int d = 0; d < 256; d++) acc += A[i * 256 + d] * B[d * 256 + j];
    C[i * 256 + j] = acc;
}

__global__ void fuse_bT_kernel(const float* __restrict__ fc1w, const float* __restrict__ M,
                               bf16* __restrict__ outT)
{
    int n = blockIdx.x, k = threadIdx.x;
    float acc = 0.f;
#pragma unroll 4
    for (int d = 0; d < 256; d++) acc += fc1w[k * 256 + d] * M[d * 256 + n];
    outT[n * 256 + k] = f2b(acc);
}

__global__ void transpose_kernel(const float* __restrict__ src, bf16* __restrict__ dst)
{
    int n = blockIdx.x, k = threadIdx.x;
    dst[n * 256 + k] = f2b(src[k * 256 + n]);
}

__global__ void biasfold_kernel(const float* __restrict__ fc1b, const float* __restrict__ M1q,
                                const float* __restrict__ M1k, const float* __restrict__ wvw,
                                const float* __restrict__ g1b, float* __restrict__ qb,
                                float* __restrict__ kb, float* __restrict__ vb)
{
    int n = threadIdx.x;
    float aq = 0.f, ak = 0.f, av = 0.f;
#pragma unroll 4
    for (int d = 0; d < 256; d++) {
        float f = fc1b[d];
        aq += f * M1q[d * 256 + n];
        ak += f * M1k[d * 256 + n];
        av += f * wvw[d * 256 + n];
    }
    qb[n] = aq + g1b[n];
    kb[n] = ak;
    vb[n] = av;
}

// ---------------------------------------------------------------- generic GEMM
__global__ __launch_bounds__(256, 3) void gemm_kernel(
    const bf16* __restrict__ A, const bf16* __restrict__ BT,
    const float* __restrict__ bias, bf16* __restrict__ Ob,
    float* __restrict__ Of, const float* __restrict__ resid, int mode)
{
    int t = threadIdx.x, lane = t & 63, w = t >> 6, quad = lane >> 4, l15 = lane & 15;
    int row0 = blockIdx.y * 128 + (w >> 1) * 64;
    int col0 = blockIdx.x * 128 + (w & 1) * 64;
    f32x4 acc[4][4];
#pragma unroll
    for (int i = 0; i < 4; i++)
#pragma unroll
        for (int j = 0; j < 4; j++) acc[i][j] = (f32x4){0.f, 0.f, 0.f, 0.f};
    const bf16* Ap = A + (size_t)(row0 + l15) * 256 + quad * 8;
    const bf16* Bp = BT + (size_t)(col0 + l15) * 256 + quad * 8;
#pragma unroll
    for (int k = 0; k < 8; k++) {
        bf16x8 af[4], bfr[4];
#pragma unroll
        for (int mt = 0; mt < 4; mt++) af[mt] = *(const bf16x8*)(Ap + mt * 16 * 256 + k * 32);
#pragma unroll
        for (int nt = 0; nt < 4; nt++) bfr[nt] = *(const bf16x8*)(Bp + nt * 16 * 256 + k * 32);
#pragma unroll
        for (int mt = 0; mt < 4; mt++)
#pragma unroll
            for (int nt = 0; nt < 4; nt++)
                acc[mt][nt] = __builtin_amdgcn_mfma_f32_16x16x32_bf16(af[mt], bfr[nt], acc[mt][nt], 0, 0, 0);
    }
#pragma unroll
    for (int mt = 0; mt < 4; mt++)
#pragma unroll
        for (int nt = 0; nt < 4; nt++) {
            int rb = row0 + mt * 16 + quad * 4;
            int c = col0 + nt * 16 + l15;
            float bv = bias ? bias[c] : 0.0f;
#pragma unroll
            for (int reg = 0; reg < 4; reg++) {
                int r = rb + reg;
                float v = acc[mt][nt][reg] + bv;
                if (mode == 0) Ob[(size_t)r * 256 + c] = f2b(v);
                else Of[(size_t)r * 256 + c] = v + resid[(size_t)r * 259 + 3 + c];
            }
        }
}

// ---------------------------------------------------------------- fused gram + top-16 KNN
// 512 threads (8 waves), 32 query rows per block, grid (128,4) -> 2 blocks/CU,
// 4 waves/SIMD. Per 256-col tile: MFMA dots -> LDS row-major (stride 260,
// 16B-aligned, 2-way aliasing = free). Selection: each wave owns 4 rows; per
// row a sorted top-16 list across lanes 0..15 (sortable-u32 keys). Per row per
// tile: ONE ds_read_b128 (4 cands/lane = full 256-col row), ballot-filter on
// min-of-4 vs current 16th (T); rare qualifiers pop via readlane + shuffle-shift.
__global__ __launch_bounds__(512, 4) void knn_kernel(
    const bf16* __restrict__ featb, const float* __restrict__ sq, int* __restrict__ idxout)
{
    __shared__ __align__(16) float lds[32 * 260];   // 33280 B
    int t = threadIdx.x, lane = t & 63, w = t >> 6, quad = lane >> 4, l15 = lane & 15;
    int b = blockIdx.y;
    int row0 = blockIdx.x * 32;
    const bf16* F = featb + (size_t)b * SS * 256;
    const float* sqb = sq + b * SS;

    unsigned int Lv[4]; int Li[4];
#pragma unroll
    for (int i = 0; i < 4; i++) { Lv[i] = 0xFFFFFFFFu; Li[i] = 0; }

    const bf16* Ap0 = F + (size_t)(row0 + l15) * 256 + quad * 8;        // rows row0..+15 (L1-resident)
    const bf16* Ap1 = Ap0 + 16 * 256;                                    // rows row0+16..+31

    for (int tile = 0; tile < 16; tile++) {
        int c0 = tile * 256;
        f32x4 acc[2][2];
#pragma unroll
        for (int i = 0; i < 2; i++)
#pragma unroll
            for (int j = 0; j < 2; j++) acc[i][j] = (f32x4){0.f, 0.f, 0.f, 0.f};
        const bf16* Bp = F + (size_t)(c0 + w * 32 + l15) * 256 + quad * 8;
#pragma unroll
        for (int k = 0; k < 8; k++) {
            bf16x8 a0 = *(const bf16x8*)(Ap0 + k * 32);
            bf16x8 a1 = *(const bf16x8*)(Ap1 + k * 32);
            bf16x8 b0 = *(const bf16x8*)(Bp + k * 32);
            bf16x8 b1 = *(const bf16x8*)(Bp + 16 * 256 + k * 32);
            acc[0][0] = __builtin_amdgcn_mfma_f32_16x16x32_bf16(a0, b0, acc[0][0], 0, 0, 0);
            acc[0][1] = __builtin_amdgcn_mfma_f32_16x16x32_bf16(a0, b1, acc[0][1], 0, 0, 0);
            acc[1][0] = __builtin_amdgcn_mfma_f32_16x16x32_bf16(a1, b0, acc[1][0], 0, 0, 0);
            acc[1][1] = __builtin_amdgcn_mfma_f32_16x16x32_bf16(a1, b1, acc[1][1], 0, 0, 0);
        }
        __syncthreads();   // previous tile's selection reads done
#pragma unroll
        for (int nt = 0; nt < 2; nt++) {
            int colL = w * 32 + nt * 16 + l15;
            float sqc = sqb[c0 + colL];
#pragma unroll
            for (int mt = 0; mt < 2; mt++) {
#pragma unroll
                for (int reg = 0; reg < 4; reg++) {
                    int rowL = mt * 16 + quad * 4 + reg;
                    lds[rowL * 260 + colL] = fmaf(-2.0f, acc[mt][nt][reg], sqc);
                }
            }
        }
        __syncthreads();
        // selection: wave w owns LDS rows w*4 .. w*4+3; one b128 per row
        f32x4 dv[4];
#pragma unroll
        for (int r = 0; r < 4; r++) dv[r] = *(const f32x4*)&lds[(w * 4 + r) * 260 + 4 * lane];
#pragma unroll 1
        for (int r = 0; r < 4; r++) {
            unsigned int Lv_r = Lv[r]; int Li_r = Li[r];
            unsigned int T = __shfl(Lv_r, 15);
            unsigned int kk[4];
#pragma unroll
            for (int j = 0; j < 4; j++) {
                unsigned int bits = __float_as_uint(dv[r][j]);
                kk[j] = bits ^ ((unsigned int)(((int)bits) >> 31) | 0x80000000u);
            }
            unsigned int kmin = min(min(kk[0], kk[1]), min(kk[2], kk[3]));
            unsigned long long mask = __ballot(kmin < T);
            while (mask) {
                int l = __ffsll(mask) - 1;
                mask &= mask - 1;
                unsigned int cv[4];
#pragma unroll
                for (int j = 0; j < 4; j++) cv[j] = __shfl(kk[j], l);
                int cb = c0 + 4 * l;
#pragma unroll
                for (int j = 0; j < 4; j++) {
                    if (cv[j] < T) {
                        int ci = cb + j;
                        bool qual = (lane < 16) && (cv[j] < Lv_r);
                        unsigned long long m2 = __ballot(qual);
                        int pos = __ffsll(m2) - 1;
                        unsigned int sv = __shfl_up(Lv_r, 1);
                        int si = __shfl_up(Li_r, 1);
                        Lv_r = (lane == pos) ? cv[j] : ((lane > pos) ? sv : Lv_r);
                        Li_r = (lane == pos) ? ci : ((lane > pos) ? si : Li_r);
                        T = __shfl(Lv_r, 15);
                    }
                }
            }
            Lv[r] = Lv_r; Li[r] = Li_r;
        }
    }
    // write out: lanes 0..15 hold the 16 nearest for each owned row
#pragma unroll 1
    for (int r = 0; r < 4; r++) {
        if (lane < 16)
            idxout[((size_t)b * SS + row0 + w * 4 + r) * 16 + lane] = Li[r];
    }
}

// ---------------------------------------------------------------- fused edge MLP
__global__ __launch_bounds__(256, 2) void edge_kernel(
    const bf16* __restrict__ qb, const bf16* __restrict__ kg1, const bf16* __restrict__ vf,
    const bf16* __restrict__ g2T, const float* __restrict__ g2b,
    const int* __restrict__ idx, bf16* __restrict__ res)
{
    __shared__ __align__(16) bf16 e1[8 * 16 * 264];
    __shared__ int nbrs[8][16];
    int t = threadIdx.x, lane = t & 63, w = t >> 6, quad = lane >> 4, l15 = lane & 15;
    int G0 = blockIdx.x * 8;
    int bb = G0 & ~(SS - 1);
    if (t < 128) {
        int g = t >> 4, r = t & 15;
        nbrs[g][r] = bb + idx[(size_t)(G0 + g) * 16 + r];
    }
    bf16x8 bg[4][8];
#pragma unroll
    for (int nt = 0; nt < 4; nt++)
#pragma unroll
        for (int k = 0; k < 8; k++)
            bg[nt][k] = *(const bf16x8*)(g2T + (size_t)(w * 64 + nt * 16 + l15) * 256 + k * 32 + quad * 8);
    __syncthreads();
#pragma unroll 4
    for (int i = 0; i < 16; i++) {
        int f = i * 256 + t;
        int c8 = f & 31, r = (f >> 5) & 15, g = f >> 9;
        int nbr = nbrs[g][r];
        bf16x8 qv = *(const bf16x8*)(qb + (size_t)(G0 + g) * 256 + c8 * 8);
        bf16x8 kv = *(const bf16x8*)(kg1 + (size_t)nbr * 256 + c8 * 8);
        bf16x8 e;
#pragma unroll
        for (int j = 0; j < 8; j++) {
            float d = b2f(qv[j]) - b2f(kv[j]);
            e[j] = f2b(fmaxf(d, 0.0f));
        }
        *(bf16x8*)(&e1[(g * 16 + r) * 264 + c8 * 8]) = e;
    }
    __syncthreads();
#pragma unroll 1
    for (int g = 0; g < 8; g++) {
        f32x4 acc[4];
#pragma unroll
        for (int nt = 0; nt < 4; nt++) acc[nt] = (f32x4){0.f, 0.f, 0.f, 0.f};
#pragma unroll
        for (int k = 0; k < 8; k++) {
            bf16x8 a = *(const bf16x8*)(&e1[(g * 16 + l15) * 264 + k * 32 + quad * 8]);
#pragma unroll
            for (int nt = 0; nt < 4; nt++)
                acc[nt] = __builtin_amdgcn_mfma_f32_16x16x32_bf16(a, bg[nt][k], acc[nt], 0, 0, 0);
        }
        int grow = G0 + g;
#pragma unroll
        for (int nt = 0; nt < 4; nt++) {
            int col = w * 64 + nt * 16 + l15;
            float b2v = g2b[col];
            float lg[4], p[4];
#pragma unroll
            for (int reg = 0; reg < 4; reg++) lg[reg] = (acc[nt][reg] + b2v) * 0.0625f;
            float mx = fmaxf(fmaxf(lg[0], lg[1]), fmaxf(lg[2], lg[3]));
            mx = fmaxf(mx, __shfl_xor(mx, 16));
            mx = fmaxf(mx, __shfl_xor(mx, 32));
            float ps = 0.f;
#pragma unroll
            for (int reg = 0; reg < 4; reg++) { p[reg] = __expf(lg[reg] - mx); ps += p[reg]; }
            ps += __shfl_xor(ps, 16);
            ps += __shfl_xor(ps, 32);
            float inv = __builtin_amdgcn_rcpf(ps);
            float rs = 0.f;
#pragma unroll
            for (int reg = 0; reg < 4; reg++) {
                int nbr = nbrs[g][quad * 4 + reg];
                rs += p[reg] * b2f(vf[(size_t)nbr * 256 + col]);
            }
            rs *= inv;
            rs += __shfl_xor(rs, 16);
            rs += __shfl_xor(rs, 32);
            if (quad == 0) res[(size_t)grow * 256 + col] = f2b(rs);
        }
    }
}

// ---------------------------------------------------------------- launcher
extern "C" void kernel_launch(void* const* d_in, const int* in_sizes, int n_in,
                              void* d_out, int out_size, void* d_ws, size_t ws_size,
                              hipStream_t stream)
{
    (void)in_sizes; (void)n_in; (void)out_size; (void)ws_size;
    const float* x    = (const float*)d_in[0];
    const float* fc1w = (const float*)d_in[1];
    const float* fc1b = (const float*)d_in[2];
    const float* fc2w = (const float*)d_in[3];
    const float* fc2b = (const float*)d_in[4];
    const float* wqw  = (const float*)d_in[5];
    const float* wkw  = (const float*)d_in[6];
    const float* wvw  = (const float*)d_in[7];
    const float* g1w  = (const float*)d_in[8];
    const float* g1b  = (const float*)d_in[9];
    const float* g2w  = (const float*)d_in[10];
    const float* g2b  = (const float*)d_in[11];

    float* pos_out = (float*)d_out;
    float* out     = (float*)d_out + (size_t)NROWS * 3;

    char* ws = (char*)d_ws;
    size_t off = 0;
    auto alloc = [&](size_t bytes) { void* p = ws + off; off += (bytes + 255) & ~(size_t)255; return p; };
    bf16* featb = (bf16*)alloc((size_t)NROWS * 256 * 2);
    bf16* qbuf  = (bf16*)alloc((size_t)NROWS * 256 * 2);
    bf16* kg    = (bf16*)alloc((size_t)NROWS * 256 * 2);
    bf16* vf    = (bf16*)alloc((size_t)NROWS * 256 * 2);
    bf16* res   = (bf16*)alloc((size_t)NROWS * 256 * 2);
    float* sq   = (float*)alloc((size_t)NROWS * 4);
    int* idx    = (int*)alloc((size_t)NROWS * 16 * 4);
    float* M1q  = (float*)alloc(65536 * 4);
    float* M1k  = (float*)alloc(65536 * 4);
    bf16* WqT   = (bf16*)alloc(65536 * 2);
    bf16* WkT   = (bf16*)alloc(65536 * 2);
    bf16* WvT   = (bf16*)alloc(65536 * 2);
    bf16* fc2T  = (bf16*)alloc(65536 * 2);
    bf16* g2T   = (bf16*)alloc(65536 * 2);
    float* qbias = (float*)alloc(256 * 4);
    float* kbias = (float*)alloc(256 * 4);
    float* vbias = (float*)alloc(256 * 4);

    prep_kernel<<<NROWS, 256, 0, stream>>>(x, pos_out, featb, sq);

    mm256_kernel<<<256, 256, 0, stream>>>(wqw, g1w, M1q);
    mm256_kernel<<<256, 256, 0, stream>>>(wkw, g1w, M1k);
    fuse_bT_kernel<<<256, 256, 0, stream>>>(fc1w, M1q, WqT);
    fuse_bT_kernel<<<256, 256, 0, stream>>>(fc1w, M1k, WkT);
    fuse_bT_kernel<<<256, 256, 0, stream>>>(fc1w, wvw, WvT);
    biasfold_kernel<<<1, 256, 0, stream>>>(fc1b, M1q, M1k, wvw, g1b, qbias, kbias, vbias);
    transpose_kernel<<<256, 256, 0, stream>>>(fc2w, fc2T);
    transpose_kernel<<<256, 256, 0, stream>>>(g2w, g2T);

    dim3 gg(2, NROWS / 128);
    gemm_kernel<<<gg, 256, 0, stream>>>(featb, WqT, qbias, qbuf, nullptr, nullptr, 0);
    gemm_kernel<<<gg, 256, 0, stream>>>(featb, WkT, kbias, kg, nullptr, nullptr, 0);
    gemm_kernel<<<gg, 256, 0, stream>>>(featb, WvT, vbias, vf, nullptr, nullptr, 0);

    knn_kernel<<<dim3(SS / 32, 4), 512, 0, stream>>>(featb, sq, idx);

    edge_kernel<<<NROWS / 8, 256, 0, stream>>>(qbuf, kg, vf, g2T, g2b, idx, res);

    gemm_kernel<<<gg, 256, 0, stream>>>(res, fc2T, fc2b, nullptr, out, x, 2);
}